// Round 2
// baseline (555.378 us; speedup 1.0000x reference)
//
#include <hip/hip_runtime.h>
#include <hip/hip_bf16.h>
#include <stdint.h>

#define BB 2
#define TB 2048
#define DB 2048
#define HB 16
#define HDB 128
#define LB 64
#define MB 4096   // B*T

typedef __hip_bfloat16 bf16;
typedef __attribute__((ext_vector_type(8))) short bf16x8;
typedef __attribute__((ext_vector_type(4))) float f32x4;

#define MFMA_16x16x32 __builtin_amdgcn_mfma_f32_16x16x32_bf16

__device__ __forceinline__ float bf2f(bf16 h) { return __bfloat162float(h); }
__device__ __forceinline__ bf16 f2bf(float f) { return __float2bfloat16(f); }

// ---------------- LayerNorm: x (4096,2048) fp32 -> xn bf16 ----------------
__global__ __launch_bounds__(256) void ln_kernel(const float* __restrict__ x,
                                                 const float* __restrict__ g,
                                                 const float* __restrict__ be,
                                                 bf16* __restrict__ xn) {
  int row = blockIdx.x, tid = threadIdx.x;
  const float4* xr = (const float4*)(x + (size_t)row * DB);
  float4 a = xr[2 * tid], b = xr[2 * tid + 1];
  float s = a.x + a.y + a.z + a.w + b.x + b.y + b.z + b.w;
  float s2 = a.x * a.x + a.y * a.y + a.z * a.z + a.w * a.w +
             b.x * b.x + b.y * b.y + b.z * b.z + b.w * b.w;
  for (int off = 32; off > 0; off >>= 1) {
    s += __shfl_down(s, off);
    s2 += __shfl_down(s2, off);
  }
  __shared__ float red[8];
  int w = tid >> 6, lane = tid & 63;
  if (lane == 0) { red[w] = s; red[4 + w] = s2; }
  __syncthreads();
  s = red[0] + red[1] + red[2] + red[3];
  s2 = red[4] + red[5] + red[6] + red[7];
  float mu = s * (1.f / DB);
  float var = s2 * (1.f / DB) - mu * mu;
  float rstd = rsqrtf(var + 1e-5f);
  const float4* gw = (const float4*)g;
  const float4* bb = (const float4*)be;
  float4 g0 = gw[2 * tid], g1 = gw[2 * tid + 1];
  float4 b0 = bb[2 * tid], b1 = bb[2 * tid + 1];
  union { bf16x8 v; bf16 e[8]; } u;
  u.e[0] = f2bf((a.x - mu) * rstd * g0.x + b0.x);
  u.e[1] = f2bf((a.y - mu) * rstd * g0.y + b0.y);
  u.e[2] = f2bf((a.z - mu) * rstd * g0.z + b0.z);
  u.e[3] = f2bf((a.w - mu) * rstd * g0.w + b0.w);
  u.e[4] = f2bf((b.x - mu) * rstd * g1.x + b1.x);
  u.e[5] = f2bf((b.y - mu) * rstd * g1.y + b1.y);
  u.e[6] = f2bf((b.z - mu) * rstd * g1.z + b1.z);
  u.e[7] = f2bf((b.w - mu) * rstd * g1.w + b1.w);
  *(bf16x8*)(xn + (size_t)row * DB + tid * 8) = u.v;
}

// ------------- transpose+convert: W fp32 (K,N) -> Wt bf16 (N,K) -----------
__global__ __launch_bounds__(256) void wconv_kernel(const float* __restrict__ W,
                                                    bf16* __restrict__ Wt) {
  __shared__ float t[32][33];
  int c0 = blockIdx.x * 32, r0 = blockIdx.y * 32;
  int tx = threadIdx.x & 31, ty = threadIdx.x >> 5;  // 32 x 8
  for (int p = 0; p < 4; ++p)
    t[ty + 8 * p][tx] = W[(size_t)(r0 + ty + 8 * p) * DB + c0 + tx];
  __syncthreads();
  for (int p = 0; p < 4; ++p)
    Wt[(size_t)(c0 + ty + 8 * p) * DB + r0 + tx] = f2bf(t[tx][ty + 8 * p]);
}

// ---------------- MFMA GEMM: C = A(4096xK) * Bt^T + bias ------------------
// A bf16 row-major (M,K); Bt bf16 row-major (N,K) (transposed weight)
// MODE 0: bf16 out + RoPE; MODE 1: bf16 out; MODE 2: fp32 out
template <int MODE>
__global__ __launch_bounds__(256) void gemm_kernel(
    const bf16* __restrict__ A, const bf16* __restrict__ Bt,
    const float* __restrict__ bias, void* __restrict__ Cout,
    const float* __restrict__ fcos, const float* __restrict__ fsin) {
  constexpr int K = DB, N = DB;
  __shared__ __align__(16) bf16 As[128 * 32];
  __shared__ __align__(16) bf16 Bs[128 * 32];
  int tid = threadIdx.x;
  int m0 = blockIdx.y * 128, n0 = blockIdx.x * 128;
  int w = tid >> 6, l = tid & 63;
  int wr = w >> 1, wc = w & 1;
  int lrow = l & 15, lk = (l >> 4) * 8;

  f32x4 zero4 = {0.f, 0.f, 0.f, 0.f};
  f32x4 acc[4][4];
  for (int m = 0; m < 4; ++m)
    for (int n = 0; n < 4; ++n) acc[m][n] = zero4;

  for (int kk = 0; kk < K / 32; ++kk) {
    int k0 = kk * 32;
    __syncthreads();
    for (int i = 0; i < 2; ++i) {
      int c = i * 256 + tid;
      int r = c >> 2, cc = c & 3;
      *(bf16x8*)&As[r * 32 + cc * 8] =
          *(const bf16x8*)&A[(size_t)(m0 + r) * K + k0 + cc * 8];
      *(bf16x8*)&Bs[r * 32 + cc * 8] =
          *(const bf16x8*)&Bt[(size_t)(n0 + r) * K + k0 + cc * 8];
    }
    __syncthreads();
    bf16x8 af[4], bfr[4];
    for (int m = 0; m < 4; ++m)
      af[m] = *(bf16x8*)&As[(wr * 64 + m * 16 + lrow) * 32 + lk];
    for (int n = 0; n < 4; ++n)
      bfr[n] = *(bf16x8*)&Bs[(wc * 64 + n * 16 + lrow) * 32 + lk];
    for (int m = 0; m < 4; ++m)
      for (int n = 0; n < 4; ++n)
        acc[m][n] = MFMA_16x16x32(af[m], bfr[n], acc[m][n], 0, 0, 0);
  }

  int rg = 4 * (l >> 4), cl = l & 15;
  for (int m = 0; m < 4; ++m) {
    int rowb = m0 + wr * 64 + m * 16 + rg;
    for (int n = 0; n < 4; ++n) {
      int col = n0 + wc * 64 + n * 16 + cl;
      float bv = bias[col];
      for (int r = 0; r < 4; ++r) {
        int rr = rowb + r;
        float v = acc[m][n][r] + bv;
        if (MODE == 0) {  // RoPE: pairs are adjacent columns; parity(col)==parity(lane)
          float pv = __shfl_xor(v, 1);
          int t = rr & (TB - 1);
          int pi = (col & 127) >> 1;
          float c = fcos[t * 64 + pi], sn = fsin[t * 64 + pi];
          v = (col & 1) ? (pv * sn + v * c) : (v * c - pv * sn);
        }
        if (MODE == 2)
          ((float*)Cout)[(size_t)rr * N + col] = v;
        else
          ((bf16*)Cout)[(size_t)rr * N + col] = f2bf(v);
      }
    }
  }
}

// ------- small projection: out(64rows x ND) = in(64 x KD) @ W + bias ------
template <int KD, int ND>
__global__ __launch_bounds__(256) void proj_kernel(const bf16* __restrict__ in,
                                                   const float* __restrict__ Wp,
                                                   const float* __restrict__ bias,
                                                   bf16* __restrict__ out) {
  constexpr int CGS = ND / 4;   // column groups of 4
  constexpr int RS = 256 / CGS; // row slots
  constexpr int RPT = 64 / RS;  // rows per thread
  __shared__ float Ws[KD * ND];
  __shared__ __align__(16) bf16 Is[64 * KD];
  int tid = threadIdx.x;
  size_t row0 = (size_t)blockIdx.x * 64;
  for (int i = tid; i < KD * ND; i += 256) Ws[i] = Wp[i];
  for (int c = tid; c < 64 * KD / 8; c += 256) {
    int r = c / (KD / 8), cc = c % (KD / 8);
    *(bf16x8*)&Is[r * KD + cc * 8] = *(const bf16x8*)&in[(row0 + r) * KD + cc * 8];
  }
  __syncthreads();
  int cg = tid % CGS, rs = tid / CGS;
  float acc[RPT][4];
  for (int i = 0; i < RPT; ++i)
    for (int j = 0; j < 4; ++j) acc[i][j] = bias[cg * 4 + j];
  for (int kx = 0; kx < KD; ++kx) {
    float4 w4 = *(const float4*)&Ws[kx * ND + cg * 4];
    for (int i = 0; i < RPT; ++i) {
      float a = bf2f(Is[(rs + i * RS) * KD + kx]);
      acc[i][0] += a * w4.x;
      acc[i][1] += a * w4.y;
      acc[i][2] += a * w4.z;
      acc[i][3] += a * w4.w;
    }
  }
  for (int i = 0; i < RPT; ++i) {
    int r = rs + i * RS;
    for (int j = 0; j < 4; ++j)
      out[(row0 + r) * ND + cg * 4 + j] = f2bf(acc[i][j]);
  }
}

// ----------------- causal flash attention over latents (L=64) -------------
// qlat/klat/vlat/aout: (B,T,H,L) bf16. Block: 64 q rows (4 waves x 16).
__global__ __launch_bounds__(256) void attn_kernel(const bf16* __restrict__ qlat,
                                                   const bf16* __restrict__ klat,
                                                   const bf16* __restrict__ vlat,
                                                   bf16* __restrict__ aout) {
  int tid = threadIdx.x, w = tid >> 6, l = tid & 63;
  int qb = blockIdx.x, h = blockIdx.y, b = blockIdx.z;
  int q0 = qb * 64;
  __shared__ __align__(16) bf16 Ks[32 * 64];
  __shared__ __align__(16) bf16 VsT[64 * 32];
  __shared__ __align__(16) bf16 Ps[4][16 * 32];
  int lrow = l & 15, lk = (l >> 4) * 8;

  const bf16* qp = qlat + ((size_t)(b * TB + q0 + w * 16 + lrow) * HB + h) * LB;
  bf16x8 qf0 = *(const bf16x8*)(qp + lk);
  bf16x8 qf1 = *(const bf16x8*)(qp + 32 + lk);

  f32x4 zero4 = {0.f, 0.f, 0.f, 0.f};
  float mr[4], ls[4];
  f32x4 o[4];
  for (int r = 0; r < 4; ++r) { mr[r] = -1e30f; ls[r] = 0.f; }
  for (int g = 0; g < 4; ++g) o[g] = zero4;
  int rbase = q0 + w * 16 + 4 * (l >> 4);
  int nkt = q0 / 32 + 2;

  for (int kt = 0; kt < nkt; ++kt) {
    int k0 = kt * 32;
    __syncthreads();
    {
      int r = tid >> 3, cc = tid & 7;
      size_t gi = ((size_t)(b * TB + k0 + r) * HB + h) * LB + cc * 8;
      *(bf16x8*)&Ks[r * 64 + cc * 8] = *(const bf16x8*)&klat[gi];
      union { bf16x8 v; bf16 e[8]; } uv;
      uv.v = *(const bf16x8*)&vlat[gi];
      for (int j = 0; j < 8; ++j) VsT[(cc * 8 + j) * 32 + r] = uv.e[j];
    }
    __syncthreads();
    f32x4 s0 = zero4, s1 = zero4;
    {
      bf16x8 k00 = *(bf16x8*)&Ks[lrow * 64 + lk];
      bf16x8 k01 = *(bf16x8*)&Ks[lrow * 64 + 32 + lk];
      bf16x8 k10 = *(bf16x8*)&Ks[(16 + lrow) * 64 + lk];
      bf16x8 k11 = *(bf16x8*)&Ks[(16 + lrow) * 64 + 32 + lk];
      s0 = MFMA_16x16x32(qf0, k00, s0, 0, 0, 0);
      s0 = MFMA_16x16x32(qf1, k01, s0, 0, 0, 0);
      s1 = MFMA_16x16x32(qf0, k10, s1, 0, 0, 0);
      s1 = MFMA_16x16x32(qf1, k11, s1, 0, 0, 0);
    }
    float sv[2][4];
    for (int r = 0; r < 4; ++r) {
      int qr = rbase + r;
      sv[0][r] = (k0 + lrow <= qr) ? s0[r] * 0.125f : -1e30f;
      sv[1][r] = (k0 + 16 + lrow <= qr) ? s1[r] * 0.125f : -1e30f;
    }
    float rm[4];
    for (int r = 0; r < 4; ++r) rm[r] = fmaxf(sv[0][r], sv[1][r]);
    for (int off = 8; off > 0; off >>= 1)
      for (int r = 0; r < 4; ++r) rm[r] = fmaxf(rm[r], __shfl_xor(rm[r], off));
    float f[4], ps[4];
    for (int r = 0; r < 4; ++r) {
      float mn = fmaxf(mr[r], rm[r]);
      f[r] = __expf(mr[r] - mn);
      mr[r] = mn;
      sv[0][r] = __expf(sv[0][r] - mn);
      sv[1][r] = __expf(sv[1][r] - mn);
      ps[r] = sv[0][r] + sv[1][r];
    }
    for (int off = 8; off > 0; off >>= 1)
      for (int r = 0; r < 4; ++r) ps[r] += __shfl_xor(ps[r], off);
    for (int r = 0; r < 4; ++r) ls[r] = ls[r] * f[r] + ps[r];
    for (int g = 0; g < 4; ++g) {
      f32x4 t = o[g];
      t[0] *= f[0]; t[1] *= f[1]; t[2] *= f[2]; t[3] *= f[3];
      o[g] = t;
    }
    for (int r = 0; r < 4; ++r) {
      Ps[w][(4 * (l >> 4) + r) * 32 + lrow] = f2bf(sv[0][r]);
      Ps[w][(4 * (l >> 4) + r) * 32 + 16 + lrow] = f2bf(sv[1][r]);
    }
    __syncthreads();
    bf16x8 pf = *(bf16x8*)&Ps[w][lrow * 32 + lk];
    for (int g = 0; g < 4; ++g) {
      bf16x8 vf = *(bf16x8*)&VsT[(g * 16 + lrow) * 32 + lk];
      o[g] = MFMA_16x16x32(pf, vf, o[g], 0, 0, 0);
    }
  }
  float inv[4];
  for (int r = 0; r < 4; ++r) inv[r] = 1.f / ls[r];
  for (int g = 0; g < 4; ++g)
    for (int r = 0; r < 4; ++r) {
      size_t row = (size_t)b * TB + rbase + r;
      aout[(row * HB + h) * LB + g * 16 + lrow] = f2bf(o[g][r] * inv[r]);
    }
}

// --------------------------------------------------------------------------
extern "C" void kernel_launch(void* const* d_in, const int* in_sizes, int n_in,
                              void* d_out, int out_size, void* d_ws, size_t ws_size,
                              hipStream_t stream) {
  const float* x    = (const float*)d_in[0];
  const float* ln_w = (const float*)d_in[2];
  const float* ln_b = (const float*)d_in[3];
  const float* wq   = (const float*)d_in[4];
  const float* bq   = (const float*)d_in[5];
  const float* wk   = (const float*)d_in[6];
  const float* bk   = (const float*)d_in[7];
  const float* wv   = (const float*)d_in[8];
  const float* bv   = (const float*)d_in[9];
  const float* wo   = (const float*)d_in[10];
  const float* bo   = (const float*)d_in[11];
  const float* wcq  = (const float*)d_in[12];
  const float* bcq  = (const float*)d_in[13];
  const float* wck  = (const float*)d_in[14];
  const float* bck  = (const float*)d_in[15];
  const float* wcv  = (const float*)d_in[16];
  const float* bcv  = (const float*)d_in[17];
  const float* wd   = (const float*)d_in[18];
  const float* bd   = (const float*)d_in[19];
  const float* fcos = (const float*)d_in[20];
  const float* fsin = (const float*)d_in[21];

  char* ws = (char*)d_ws;
  bf16* xn    = (bf16*)(ws);                 // 16.8 MB
  bf16* wslot = (bf16*)(ws + 16777216);      //  8.4 MB (reused for each weight)
  bf16* qb_   = (bf16*)(ws + 25165824);      // 16.8 MB
  bf16* kb_   = (bf16*)(ws + 41943040);      // 16.8 MB
  bf16* vb_   = (bf16*)(ws + 58720256);      // 16.8 MB
  bf16* qlat  = (bf16*)(ws + 75497472);      //  8.4 MB
  bf16* klat  = (bf16*)(ws + 83886080);      //  8.4 MB
  bf16* vlat  = (bf16*)(ws + 92274688);      //  8.4 MB
  bf16* aoutp = qb_;  // reuse (q dead after latents)
  bf16* y1    = xn;   // reuse (xn dead after QKV GEMMs)

  dim3 tg(64, 64);    // weight transpose grid
  dim3 gg(16, 32);    // GEMM grid: N/128 x M/128

  ln_kernel<<<MB, 256, 0, stream>>>(x, ln_w, ln_b, xn);

  wconv_kernel<<<tg, 256, 0, stream>>>(wq, wslot);
  gemm_kernel<0><<<gg, 256, 0, stream>>>(xn, wslot, bq, qb_, fcos, fsin);
  wconv_kernel<<<tg, 256, 0, stream>>>(wk, wslot);
  gemm_kernel<0><<<gg, 256, 0, stream>>>(xn, wslot, bk, kb_, fcos, fsin);
  wconv_kernel<<<tg, 256, 0, stream>>>(wv, wslot);
  gemm_kernel<1><<<gg, 256, 0, stream>>>(xn, wslot, bv, vb_, fcos, fsin);

  proj_kernel<128, 64><<<1024, 256, 0, stream>>>(qb_, wcq, bcq, qlat);
  proj_kernel<128, 64><<<1024, 256, 0, stream>>>(kb_, wck, bck, klat);
  proj_kernel<128, 64><<<1024, 256, 0, stream>>>(vb_, wcv, bcv, vlat);

  attn_kernel<<<dim3(32, HB, BB), 256, 0, stream>>>(qlat, klat, vlat, aoutp);

  proj_kernel<64, 128><<<1024, 256, 0, stream>>>(aoutp, wd, bd, y1);

  wconv_kernel<<<tg, 256, 0, stream>>>(wo, wslot);
  gemm_kernel<2><<<gg, 256, 0, stream>>>(y1, wslot, bo, d_out, fcos, fsin);
}

// Round 3
// 379.790 us; speedup vs baseline: 1.4623x; 1.4623x over previous
//
#include <hip/hip_runtime.h>
#include <hip/hip_bf16.h>
#include <stdint.h>

#define BB 2
#define TB 2048
#define DB 2048
#define HB 16
#define HDB 128
#define LB 64
#define MB 4096   // B*T

typedef __hip_bfloat16 bf16;
typedef __attribute__((ext_vector_type(8))) short bf16x8;
typedef __attribute__((ext_vector_type(4))) float f32x4;

#define MFMA_16x16x32 __builtin_amdgcn_mfma_f32_16x16x32_bf16

typedef __attribute__((address_space(3))) void lds_t;
typedef const __attribute__((address_space(1))) void gvm_t;

__device__ __forceinline__ float bf2f(bf16 h) { return __bfloat162float(h); }
__device__ __forceinline__ bf16 f2bf(float f) { return __float2bfloat16(f); }

// ---------------- LayerNorm: x (4096,2048) fp32 -> xn bf16 ----------------
__global__ __launch_bounds__(256) void ln_kernel(const float* __restrict__ x,
                                                 const float* __restrict__ g,
                                                 const float* __restrict__ be,
                                                 bf16* __restrict__ xn) {
  int row = blockIdx.x, tid = threadIdx.x;
  const float4* xr = (const float4*)(x + (size_t)row * DB);
  float4 a = xr[2 * tid], b = xr[2 * tid + 1];
  float s = a.x + a.y + a.z + a.w + b.x + b.y + b.z + b.w;
  float s2 = a.x * a.x + a.y * a.y + a.z * a.z + a.w * a.w +
             b.x * b.x + b.y * b.y + b.z * b.z + b.w * b.w;
  for (int off = 32; off > 0; off >>= 1) {
    s += __shfl_down(s, off);
    s2 += __shfl_down(s2, off);
  }
  __shared__ float red[8];
  int w = tid >> 6, lane = tid & 63;
  if (lane == 0) { red[w] = s; red[4 + w] = s2; }
  __syncthreads();
  s = red[0] + red[1] + red[2] + red[3];
  s2 = red[4] + red[5] + red[6] + red[7];
  float mu = s * (1.f / DB);
  float var = s2 * (1.f / DB) - mu * mu;
  float rstd = rsqrtf(var + 1e-5f);
  const float4* gw = (const float4*)g;
  const float4* bb = (const float4*)be;
  float4 g0 = gw[2 * tid], g1 = gw[2 * tid + 1];
  float4 b0 = bb[2 * tid], b1 = bb[2 * tid + 1];
  union { bf16x8 v; bf16 e[8]; } u;
  u.e[0] = f2bf((a.x - mu) * rstd * g0.x + b0.x);
  u.e[1] = f2bf((a.y - mu) * rstd * g0.y + b0.y);
  u.e[2] = f2bf((a.z - mu) * rstd * g0.z + b0.z);
  u.e[3] = f2bf((a.w - mu) * rstd * g0.w + b0.w);
  u.e[4] = f2bf((b.x - mu) * rstd * g1.x + b1.x);
  u.e[5] = f2bf((b.y - mu) * rstd * g1.y + b1.y);
  u.e[6] = f2bf((b.z - mu) * rstd * g1.z + b1.z);
  u.e[7] = f2bf((b.w - mu) * rstd * g1.w + b1.w);
  *(bf16x8*)(xn + (size_t)row * DB + tid * 8) = u.v;
}

// ------------- transpose+convert: W fp32 (K,N) -> Wt bf16 (N,K) -----------
__global__ __launch_bounds__(256) void wconv_kernel(const float* __restrict__ W,
                                                    bf16* __restrict__ Wt) {
  __shared__ float t[32][33];
  int c0 = blockIdx.x * 32, r0 = blockIdx.y * 32;
  int tx = threadIdx.x & 31, ty = threadIdx.x >> 5;  // 32 x 8
  for (int p = 0; p < 4; ++p)
    t[ty + 8 * p][tx] = W[(size_t)(r0 + ty + 8 * p) * DB + c0 + tx];
  __syncthreads();
  for (int p = 0; p < 4; ++p)
    Wt[(size_t)(c0 + ty + 8 * p) * DB + r0 + tx] = f2bf(t[tx][ty + 8 * p]);
}

// ---------------- MFMA GEMM: C = A(4096xK) * Bt^T + bias ------------------
// A bf16 row-major (M,K); Bt bf16 row-major (N,K) (transposed weight)
// MODE 0: bf16 out + RoPE; MODE 1: bf16 out; MODE 2: fp32 out
template <int MODE>
__global__ __launch_bounds__(256) void gemm_kernel(
    const bf16* __restrict__ A, const bf16* __restrict__ Bt,
    const float* __restrict__ bias, void* __restrict__ Cout,
    const float* __restrict__ fcos, const float* __restrict__ fsin) {
  constexpr int K = DB, N = DB;
  __shared__ __align__(16) bf16 As[128 * 32];
  __shared__ __align__(16) bf16 Bs[128 * 32];
  int tid = threadIdx.x;
  int m0 = blockIdx.y * 128, n0 = blockIdx.x * 128;
  int w = tid >> 6, l = tid & 63;
  int wr = w >> 1, wc = w & 1;
  int lrow = l & 15, lk = (l >> 4) * 8;

  f32x4 zero4 = {0.f, 0.f, 0.f, 0.f};
  f32x4 acc[4][4];
  for (int m = 0; m < 4; ++m)
    for (int n = 0; n < 4; ++n) acc[m][n] = zero4;

  for (int kk = 0; kk < K / 32; ++kk) {
    int k0 = kk * 32;
    __syncthreads();
#pragma unroll
    for (int i = 0; i < 2; ++i) {
      int c = i * 256 + tid;
      int r = c >> 2, cc = c & 3;
      int cb = i * 256 + (tid & ~63);  // wave-uniform LDS base (lane*16B added by HW)
      __builtin_amdgcn_global_load_lds(
          (gvm_t*)&A[(size_t)(m0 + r) * K + k0 + cc * 8], (lds_t*)&As[cb * 8], 16, 0, 0);
      __builtin_amdgcn_global_load_lds(
          (gvm_t*)&Bt[(size_t)(n0 + r) * K + k0 + cc * 8], (lds_t*)&Bs[cb * 8], 16, 0, 0);
    }
    __syncthreads();
    bf16x8 af[4], bfr[4];
    for (int m = 0; m < 4; ++m)
      af[m] = *(bf16x8*)&As[(wr * 64 + m * 16 + lrow) * 32 + lk];
    for (int n = 0; n < 4; ++n)
      bfr[n] = *(bf16x8*)&Bs[(wc * 64 + n * 16 + lrow) * 32 + lk];
    for (int m = 0; m < 4; ++m)
      for (int n = 0; n < 4; ++n)
        acc[m][n] = MFMA_16x16x32(af[m], bfr[n], acc[m][n], 0, 0, 0);
  }

  int rg = 4 * (l >> 4), cl = l & 15;
  for (int m = 0; m < 4; ++m) {
    int rowb = m0 + wr * 64 + m * 16 + rg;
    for (int n = 0; n < 4; ++n) {
      int col = n0 + wc * 64 + n * 16 + cl;
      float bv = bias[col];
      for (int r = 0; r < 4; ++r) {
        int rr = rowb + r;
        float v = acc[m][n][r] + bv;
        if (MODE == 0) {  // RoPE: pairs are adjacent columns; parity(col)==parity(lane)
          float pv = __shfl_xor(v, 1);
          int t = rr & (TB - 1);
          int pi = (col & 127) >> 1;
          float c = fcos[t * 64 + pi], sn = fsin[t * 64 + pi];
          v = (col & 1) ? (pv * sn + v * c) : (v * c - pv * sn);
        }
        if (MODE == 2)
          ((float*)Cout)[(size_t)rr * N + col] = v;
        else
          ((bf16*)Cout)[(size_t)rr * N + col] = f2bf(v);
      }
    }
  }
}

// ------- small projection: out(64rows x ND) = in(64 x KD) @ W + bias ------
template <int KD, int ND>
__global__ __launch_bounds__(256) void proj_kernel(const bf16* __restrict__ in,
                                                   const float* __restrict__ Wp,
                                                   const float* __restrict__ bias,
                                                   bf16* __restrict__ out) {
  constexpr int CGS = ND / 4;   // column groups of 4
  constexpr int RS = 256 / CGS; // row slots
  constexpr int RPT = 64 / RS;  // rows per thread
  __shared__ float Ws[KD * ND];
  __shared__ __align__(16) bf16 Is[64 * KD];
  int tid = threadIdx.x;
  size_t row0 = (size_t)blockIdx.x * 64;
  for (int i = tid; i < KD * ND; i += 256) Ws[i] = Wp[i];
  for (int c = tid; c < 64 * KD / 8; c += 256) {
    int r = c / (KD / 8), cc = c % (KD / 8);
    *(bf16x8*)&Is[r * KD + cc * 8] = *(const bf16x8*)&in[(row0 + r) * KD + cc * 8];
  }
  __syncthreads();
  int cg = tid % CGS, rs = tid / CGS;
  float acc[RPT][4];
  for (int i = 0; i < RPT; ++i)
    for (int j = 0; j < 4; ++j) acc[i][j] = bias[cg * 4 + j];
  for (int kx = 0; kx < KD; ++kx) {
    float4 w4 = *(const float4*)&Ws[kx * ND + cg * 4];
    for (int i = 0; i < RPT; ++i) {
      float a = bf2f(Is[(rs + i * RS) * KD + kx]);
      acc[i][0] += a * w4.x;
      acc[i][1] += a * w4.y;
      acc[i][2] += a * w4.z;
      acc[i][3] += a * w4.w;
    }
  }
  for (int i = 0; i < RPT; ++i) {
    int r = rs + i * RS;
    for (int j = 0; j < 4; ++j)
      out[(row0 + r) * ND + cg * 4 + j] = f2bf(acc[i][j]);
  }
}

// ----------------- causal flash attention over latents (L=64) -------------
// qlat/klat/vlat/aout: (B,T,H,L) bf16.
// Block handles TWO 64-row q-tiles {31-p, p} (constant total work = 33 units).
// 4 waves x 16 q rows; KVBLK=64; LDS tiles XOR-swizzled on 8-elem granules.
#define SWZ8(row) ((((row) ^ ((row) >> 3)) & 7) << 3)
__global__ __launch_bounds__(256) void attn_kernel(const bf16* __restrict__ qlat,
                                                   const bf16* __restrict__ klat,
                                                   const bf16* __restrict__ vlat,
                                                   bf16* __restrict__ aout) {
  int tid = threadIdx.x, w = tid >> 6, l = tid & 63;
  int h = blockIdx.y, b = blockIdx.z;
  int lrow = l & 15, lk = (l >> 4) * 8, hi4 = l >> 4;
  __shared__ __align__(16) bf16 Ks[64 * 64];
  __shared__ __align__(16) bf16 VsT[64 * 64];
  __shared__ __align__(16) bf16 Ps[4][16 * 64];

  f32x4 zero4 = {0.f, 0.f, 0.f, 0.f};
  for (int half = 0; half < 2; ++half) {
    int tile = half ? (int)blockIdx.x : 31 - (int)blockIdx.x;
    int q0 = tile * 64;
    const bf16* qp = qlat + ((size_t)(b * TB + q0 + w * 16 + lrow) * HB + h) * LB;
    bf16x8 qf0 = *(const bf16x8*)(qp + lk);
    bf16x8 qf1 = *(const bf16x8*)(qp + 32 + lk);
    float mr[4], ls[4];
    f32x4 o[4];
    for (int r = 0; r < 4; ++r) { mr[r] = -1e30f; ls[r] = 0.f; }
    for (int n = 0; n < 4; ++n) o[n] = zero4;

    for (int kt = 0; kt <= tile; ++kt) {
      int kv0 = kt * 64;
      __syncthreads();
#pragma unroll
      for (int i = 0; i < 2; ++i) {
        int c = i * 256 + tid;
        int kr = c >> 3, cc = c & 7;
        size_t gbase = ((size_t)(b * TB + kv0 + kr) * HB + h) * LB + cc * 8;
        *(bf16x8*)&Ks[kr * 64 + ((cc * 8) ^ SWZ8(kr))] = *(const bf16x8*)&klat[gbase];
        union { bf16x8 v; bf16 e[8]; } uv;
        uv.v = *(const bf16x8*)&vlat[gbase];
#pragma unroll
        for (int j = 0; j < 8; ++j) {
          int n = cc * 8 + j;
          VsT[n * 64 + (kr ^ SWZ8(n))] = uv.e[j];
        }
      }
      __syncthreads();
      // QK^T: S (16 q x 64 kv) per wave
      f32x4 s[4];
#pragma unroll
      for (int kg = 0; kg < 4; ++kg) {
        int row = kg * 16 + lrow;
        int sw = SWZ8(row);
        bf16x8 kf0 = *(bf16x8*)&Ks[row * 64 + ((0 + lk) ^ sw)];
        bf16x8 kf1 = *(bf16x8*)&Ks[row * 64 + ((32 + lk) ^ sw)];
        f32x4 a = zero4;
        a = MFMA_16x16x32(qf0, kf0, a, 0, 0, 0);
        a = MFMA_16x16x32(qf1, kf1, a, 0, 0, 0);
        s[kg] = a;
      }
      // scale + mask (diag tile only; wave-uniform branch)
      float sc[4][4];
      bool diag = (kt == tile);
#pragma unroll
      for (int kg = 0; kg < 4; ++kg)
#pragma unroll
        for (int r = 0; r < 4; ++r) {
          float v = s[kg][r] * 0.125f;
          if (diag) {
            int kvg = kv0 + kg * 16 + lrow;
            int qr = q0 + w * 16 + 4 * hi4 + r;
            if (kvg > qr) v = -1e30f;
          }
          sc[kg][r] = v;
        }
      // online softmax
      float rm[4], f[4], psum[4];
#pragma unroll
      for (int r = 0; r < 4; ++r)
        rm[r] = fmaxf(fmaxf(sc[0][r], sc[1][r]), fmaxf(sc[2][r], sc[3][r]));
      for (int off = 8; off > 0; off >>= 1)
#pragma unroll
        for (int r = 0; r < 4; ++r) rm[r] = fmaxf(rm[r], __shfl_xor(rm[r], off));
#pragma unroll
      for (int r = 0; r < 4; ++r) {
        float mn = fmaxf(mr[r], rm[r]);
        f[r] = __expf(mr[r] - mn);
        mr[r] = mn;
      }
#pragma unroll
      for (int kg = 0; kg < 4; ++kg)
#pragma unroll
        for (int r = 0; r < 4; ++r) sc[kg][r] = __expf(sc[kg][r] - mr[r]);
#pragma unroll
      for (int r = 0; r < 4; ++r)
        psum[r] = sc[0][r] + sc[1][r] + sc[2][r] + sc[3][r];
      for (int off = 8; off > 0; off >>= 1)
#pragma unroll
        for (int r = 0; r < 4; ++r) psum[r] += __shfl_xor(psum[r], off);
#pragma unroll
      for (int r = 0; r < 4; ++r) ls[r] = ls[r] * f[r] + psum[r];
#pragma unroll
      for (int n = 0; n < 4; ++n) {
        f32x4 t = o[n];
        t[0] *= f[0]; t[1] *= f[1]; t[2] *= f[2]; t[3] *= f[3];
        o[n] = t;
      }
      // stage P (per-wave buffer; no cross-wave barrier needed)
#pragma unroll
      for (int r = 0; r < 4; ++r) {
        int rq = 4 * hi4 + r;
        int sw = SWZ8(rq);
#pragma unroll
        for (int kg = 0; kg < 4; ++kg)
          Ps[w][rq * 64 + ((kg * 16 + lrow) ^ sw)] = f2bf(sc[kg][r]);
      }
      int swp = SWZ8(lrow);
      bf16x8 pa0 = *(bf16x8*)&Ps[w][lrow * 64 + ((0 + lk) ^ swp)];
      bf16x8 pa1 = *(bf16x8*)&Ps[w][lrow * 64 + ((32 + lk) ^ swp)];
      // PV: o += P @ V
#pragma unroll
      for (int n = 0; n < 4; ++n) {
        int row = n * 16 + lrow;
        int sw = SWZ8(row);
        bf16x8 vf0 = *(bf16x8*)&VsT[row * 64 + ((0 + lk) ^ sw)];
        bf16x8 vf1 = *(bf16x8*)&VsT[row * 64 + ((32 + lk) ^ sw)];
        o[n] = MFMA_16x16x32(pa0, vf0, o[n], 0, 0, 0);
        o[n] = MFMA_16x16x32(pa1, vf1, o[n], 0, 0, 0);
      }
    }
    float inv[4];
#pragma unroll
    for (int r = 0; r < 4; ++r) inv[r] = 1.f / ls[r];
#pragma unroll
    for (int n = 0; n < 4; ++n)
#pragma unroll
      for (int r = 0; r < 4; ++r) {
        size_t row = (size_t)b * TB + q0 + w * 16 + 4 * hi4 + r;
        aout[(row * HB + h) * LB + n * 16 + lrow] = f2bf(o[n][r] * inv[r]);
      }
  }
}

// --------------------------------------------------------------------------
extern "C" void kernel_launch(void* const* d_in, const int* in_sizes, int n_in,
                              void* d_out, int out_size, void* d_ws, size_t ws_size,
                              hipStream_t stream) {
  const float* x    = (const float*)d_in[0];
  const float* ln_w = (const float*)d_in[2];
  const float* ln_b = (const float*)d_in[3];
  const float* wq   = (const float*)d_in[4];
  const float* bq   = (const float*)d_in[5];
  const float* wk   = (const float*)d_in[6];
  const float* bk   = (const float*)d_in[7];
  const float* wv   = (const float*)d_in[8];
  const float* bv   = (const float*)d_in[9];
  const float* wo   = (const float*)d_in[10];
  const float* bo   = (const float*)d_in[11];
  const float* wcq  = (const float*)d_in[12];
  const float* bcq  = (const float*)d_in[13];
  const float* wck  = (const float*)d_in[14];
  const float* bck  = (const float*)d_in[15];
  const float* wcv  = (const float*)d_in[16];
  const float* bcv  = (const float*)d_in[17];
  const float* wd   = (const float*)d_in[18];
  const float* bd   = (const float*)d_in[19];
  const float* fcos = (const float*)d_in[20];
  const float* fsin = (const float*)d_in[21];

  char* ws = (char*)d_ws;
  bf16* xn    = (bf16*)(ws);                 // 16.8 MB
  bf16* wslot = (bf16*)(ws + 16777216);      //  8.4 MB (reused for each weight)
  bf16* qb_   = (bf16*)(ws + 25165824);      // 16.8 MB
  bf16* kb_   = (bf16*)(ws + 41943040);      // 16.8 MB
  bf16* vb_   = (bf16*)(ws + 58720256);      // 16.8 MB
  bf16* qlat  = (bf16*)(ws + 75497472);      //  8.4 MB
  bf16* klat  = (bf16*)(ws + 83886080);      //  8.4 MB
  bf16* vlat  = (bf16*)(ws + 92274688);      //  8.4 MB
  bf16* aoutp = qb_;  // reuse (q dead after latents)
  bf16* y1    = xn;   // reuse (xn dead after QKV GEMMs)

  dim3 tg(64, 64);    // weight transpose grid
  dim3 gg(16, 32);    // GEMM grid: N/128 x M/128

  ln_kernel<<<MB, 256, 0, stream>>>(x, ln_w, ln_b, xn);

  wconv_kernel<<<tg, 256, 0, stream>>>(wq, wslot);
  gemm_kernel<0><<<gg, 256, 0, stream>>>(xn, wslot, bq, qb_, fcos, fsin);
  wconv_kernel<<<tg, 256, 0, stream>>>(wk, wslot);
  gemm_kernel<0><<<gg, 256, 0, stream>>>(xn, wslot, bk, kb_, fcos, fsin);
  wconv_kernel<<<tg, 256, 0, stream>>>(wv, wslot);
  gemm_kernel<1><<<gg, 256, 0, stream>>>(xn, wslot, bv, vb_, fcos, fsin);

  proj_kernel<128, 64><<<1024, 256, 0, stream>>>(qb_, wcq, bcq, qlat);
  proj_kernel<128, 64><<<1024, 256, 0, stream>>>(kb_, wck, bck, klat);
  proj_kernel<128, 64><<<1024, 256, 0, stream>>>(vb_, wcv, bcv, vlat);

  attn_kernel<<<dim3(16, HB, BB), 256, 0, stream>>>(qlat, klat, vlat, aoutp);

  proj_kernel<64, 128><<<1024, 256, 0, stream>>>(aoutp, wd, bd, y1);

  wconv_kernel<<<tg, 256, 0, stream>>>(wo, wslot);
  gemm_kernel<2><<<gg, 256, 0, stream>>>(y1, wslot, bo, d_out, fcos, fsin);
}

// Round 4
// 359.183 us; speedup vs baseline: 1.5462x; 1.0574x over previous
//
#include <hip/hip_runtime.h>
#include <hip/hip_bf16.h>
#include <stdint.h>

#define BB 2
#define TB 2048
#define DB 2048
#define HB 16
#define HDB 128
#define LB 64
#define MB 4096   // B*T

typedef __hip_bfloat16 bf16;
typedef __attribute__((ext_vector_type(8))) short bf16x8;
typedef __attribute__((ext_vector_type(4))) float f32x4;

#define MFMA_16x16x32 __builtin_amdgcn_mfma_f32_16x16x32_bf16

typedef __attribute__((address_space(3))) void lds_t;
typedef const __attribute__((address_space(1))) void gvm_t;

static __device__ __forceinline__ float bf2f(bf16 h) { return __bfloat162float(h); }
static __device__ __forceinline__ bf16 f2bf(float f) { return __float2bfloat16(f); }
union BV8 { bf16x8 v; bf16 e[8]; };
static __device__ __forceinline__ float bfel(bf16x8 v, int e) { BV8 u; u.v = v; return bf2f(u.e[e]); }

// chunk-granule XOR swizzle (16B chunks within a 128B row)
#define SWZC(r) (((r) ^ ((r) >> 3)) & 7)

// ---------------- LayerNorm: x (4096,2048) fp32 -> xn bf16 ----------------
__global__ __launch_bounds__(256) void ln_kernel(const float* __restrict__ x,
                                                 const float* __restrict__ g,
                                                 const float* __restrict__ be,
                                                 bf16* __restrict__ xn) {
  int row = blockIdx.x, tid = threadIdx.x;
  const float4* xr = (const float4*)(x + (size_t)row * DB);
  float4 a = xr[2 * tid], b = xr[2 * tid + 1];
  float s = a.x + a.y + a.z + a.w + b.x + b.y + b.z + b.w;
  float s2 = a.x * a.x + a.y * a.y + a.z * a.z + a.w * a.w +
             b.x * b.x + b.y * b.y + b.z * b.z + b.w * b.w;
  for (int off = 32; off > 0; off >>= 1) {
    s += __shfl_down(s, off);
    s2 += __shfl_down(s2, off);
  }
  __shared__ float red[8];
  int w = tid >> 6, lane = tid & 63;
  if (lane == 0) { red[w] = s; red[4 + w] = s2; }
  __syncthreads();
  s = red[0] + red[1] + red[2] + red[3];
  s2 = red[4] + red[5] + red[6] + red[7];
  float mu = s * (1.f / DB);
  float var = s2 * (1.f / DB) - mu * mu;
  float rstd = rsqrtf(var + 1e-5f);
  const float4* gw = (const float4*)g;
  const float4* bb = (const float4*)be;
  float4 g0 = gw[2 * tid], g1 = gw[2 * tid + 1];
  float4 b0 = bb[2 * tid], b1 = bb[2 * tid + 1];
  BV8 u;
  u.e[0] = f2bf((a.x - mu) * rstd * g0.x + b0.x);
  u.e[1] = f2bf((a.y - mu) * rstd * g0.y + b0.y);
  u.e[2] = f2bf((a.z - mu) * rstd * g0.z + b0.z);
  u.e[3] = f2bf((a.w - mu) * rstd * g0.w + b0.w);
  u.e[4] = f2bf((b.x - mu) * rstd * g1.x + b1.x);
  u.e[5] = f2bf((b.y - mu) * rstd * g1.y + b1.y);
  u.e[6] = f2bf((b.z - mu) * rstd * g1.z + b1.z);
  u.e[7] = f2bf((b.w - mu) * rstd * g1.w + b1.w);
  *(bf16x8*)(xn + (size_t)row * DB + tid * 8) = u.v;
}

// ------------- transpose+convert: W fp32 (K,N) -> Wt bf16 (N,K) -----------
__global__ __launch_bounds__(256) void wconv_kernel(const float* __restrict__ W,
                                                    bf16* __restrict__ Wt) {
  __shared__ float t[32][33];
  int c0 = blockIdx.x * 32, r0 = blockIdx.y * 32;
  int tx = threadIdx.x & 31, ty = threadIdx.x >> 5;  // 32 x 8
  for (int p = 0; p < 4; ++p)
    t[ty + 8 * p][tx] = W[(size_t)(r0 + ty + 8 * p) * DB + c0 + tx];
  __syncthreads();
  for (int p = 0; p < 4; ++p)
    Wt[(size_t)(c0 + ty + 8 * p) * DB + r0 + tx] = f2bf(t[tx][ty + 8 * p]);
}

// ------------- fused QKV GEMM: [q|k|v](4096x6144) = xn @ WqkvT + b ---------
// Bt bf16 row-major (6144, 2048); RoPE applied for q,k blocks.
__global__ __launch_bounds__(256) void gemm_qkv_kernel(
    const bf16* __restrict__ A, const bf16* __restrict__ Bt,
    const float* __restrict__ bq, const float* __restrict__ bk,
    const float* __restrict__ bv,
    bf16* __restrict__ outq, bf16* __restrict__ outk, bf16* __restrict__ outv,
    const float* __restrict__ fcos, const float* __restrict__ fsin) {
  constexpr int K = DB;
  __shared__ __align__(16) bf16 As[128 * 32];
  __shared__ __align__(16) bf16 Bs[128 * 32];
  int tid = threadIdx.x;
  int m0 = blockIdx.y * 128, n0 = blockIdx.x * 128;
  int w = tid >> 6, l = tid & 63;
  int wr = w >> 1, wc = w & 1;
  int lrow = l & 15, lk = (l >> 4) * 8;

  f32x4 zero4 = {0.f, 0.f, 0.f, 0.f};
  f32x4 acc[4][4];
  for (int m = 0; m < 4; ++m)
    for (int n = 0; n < 4; ++n) acc[m][n] = zero4;

  for (int kk = 0; kk < K / 32; ++kk) {
    int k0 = kk * 32;
    __syncthreads();
#pragma unroll
    for (int i = 0; i < 2; ++i) {
      int c = i * 256 + tid;
      int r = c >> 2, cc = c & 3;
      int cb = i * 256 + (tid & ~63);
      __builtin_amdgcn_global_load_lds(
          (gvm_t*)&A[(size_t)(m0 + r) * K + k0 + cc * 8], (lds_t*)&As[cb * 8], 16, 0, 0);
      __builtin_amdgcn_global_load_lds(
          (gvm_t*)&Bt[(size_t)(n0 + r) * K + k0 + cc * 8], (lds_t*)&Bs[cb * 8], 16, 0, 0);
    }
    __syncthreads();
    bf16x8 af[4], bfr[4];
    for (int m = 0; m < 4; ++m)
      af[m] = *(bf16x8*)&As[(wr * 64 + m * 16 + lrow) * 32 + lk];
    for (int n = 0; n < 4; ++n)
      bfr[n] = *(bf16x8*)&Bs[(wc * 64 + n * 16 + lrow) * 32 + lk];
    __builtin_amdgcn_s_setprio(1);
    for (int m = 0; m < 4; ++m)
      for (int n = 0; n < 4; ++n)
        acc[m][n] = MFMA_16x16x32(af[m], bfr[n], acc[m][n], 0, 0, 0);
    __builtin_amdgcn_s_setprio(0);
  }

  int sel = n0 >> 11;  // 0=q, 1=k, 2=v (wave-uniform)
  const float* bias = sel == 0 ? bq : (sel == 1 ? bk : bv);
  bf16* outp = sel == 0 ? outq : (sel == 1 ? outk : outv);
  int rg = 4 * (l >> 4), cl = l & 15;
  for (int m = 0; m < 4; ++m) {
    int rowb = m0 + wr * 64 + m * 16 + rg;
    for (int n = 0; n < 4; ++n) {
      int col = n0 + wc * 64 + n * 16 + cl;
      int colL = col & 2047;
      float bv_ = bias[colL];
      for (int r = 0; r < 4; ++r) {
        int rr = rowb + r;
        float v = acc[m][n][r] + bv_;
        if (sel < 2) {  // RoPE: pairs adjacent cols; parity(col)==parity(lane)
          float pv = __shfl_xor(v, 1);
          int t = rr & (TB - 1);
          int pi = (col & 127) >> 1;
          float c = fcos[t * 64 + pi], sn = fsin[t * 64 + pi];
          v = (col & 1) ? (pv * sn + v * c) : (v * c - pv * sn);
        }
        outp[(size_t)rr * 2048 + colL] = f2bf(v);
      }
    }
  }
}

// ---------------- final GEMM: out(4096x2048 fp32) = y1 @ WoT + bo ----------
__global__ __launch_bounds__(256) void gemm_out_kernel(
    const bf16* __restrict__ A, const bf16* __restrict__ Bt,
    const float* __restrict__ bias, float* __restrict__ Cout) {
  constexpr int K = DB, N = DB;
  __shared__ __align__(16) bf16 As[128 * 32];
  __shared__ __align__(16) bf16 Bs[128 * 32];
  int tid = threadIdx.x;
  int m0 = blockIdx.y * 128, n0 = blockIdx.x * 128;
  int w = tid >> 6, l = tid & 63;
  int wr = w >> 1, wc = w & 1;
  int lrow = l & 15, lk = (l >> 4) * 8;

  f32x4 zero4 = {0.f, 0.f, 0.f, 0.f};
  f32x4 acc[4][4];
  for (int m = 0; m < 4; ++m)
    for (int n = 0; n < 4; ++n) acc[m][n] = zero4;

  for (int kk = 0; kk < K / 32; ++kk) {
    int k0 = kk * 32;
    __syncthreads();
#pragma unroll
    for (int i = 0; i < 2; ++i) {
      int c = i * 256 + tid;
      int r = c >> 2, cc = c & 3;
      int cb = i * 256 + (tid & ~63);
      __builtin_amdgcn_global_load_lds(
          (gvm_t*)&A[(size_t)(m0 + r) * K + k0 + cc * 8], (lds_t*)&As[cb * 8], 16, 0, 0);
      __builtin_amdgcn_global_load_lds(
          (gvm_t*)&Bt[(size_t)(n0 + r) * K + k0 + cc * 8], (lds_t*)&Bs[cb * 8], 16, 0, 0);
    }
    __syncthreads();
    bf16x8 af[4], bfr[4];
    for (int m = 0; m < 4; ++m)
      af[m] = *(bf16x8*)&As[(wr * 64 + m * 16 + lrow) * 32 + lk];
    for (int n = 0; n < 4; ++n)
      bfr[n] = *(bf16x8*)&Bs[(wc * 64 + n * 16 + lrow) * 32 + lk];
    __builtin_amdgcn_s_setprio(1);
    for (int m = 0; m < 4; ++m)
      for (int n = 0; n < 4; ++n)
        acc[m][n] = MFMA_16x16x32(af[m], bfr[n], acc[m][n], 0, 0, 0);
    __builtin_amdgcn_s_setprio(0);
  }

  int rg = 4 * (l >> 4), cl = l & 15;
  for (int m = 0; m < 4; ++m) {
    int rowb = m0 + wr * 64 + m * 16 + rg;
    for (int n = 0; n < 4; ++n) {
      int col = n0 + wc * 64 + n * 16 + cl;
      float bv = bias[col];
      for (int r = 0; r < 4; ++r)
        Cout[(size_t)(rowb + r) * N + col] = acc[m][n][r] + bv;
    }
  }
}

// ------- q/k latent projection: (65536 x 128) @ (128x64) + b -> (.. x 64) --
__global__ __launch_bounds__(256) void projqk_kernel(
    const bf16* __restrict__ qb, const bf16* __restrict__ kb,
    const float* __restrict__ wcq, const float* __restrict__ wck,
    const float* __restrict__ bcq, const float* __restrict__ bck,
    bf16* __restrict__ qlat, bf16* __restrict__ klat) {
  const bf16* in = blockIdx.y ? kb : qb;
  const float* Wp = blockIdx.y ? wck : wcq;
  const float* bias = blockIdx.y ? bck : bcq;
  bf16* out = blockIdx.y ? klat : qlat;
  __shared__ float Ws[128 * 64];
  __shared__ __align__(16) bf16 Is[64 * 128];
  int tid = threadIdx.x;
  size_t row0 = (size_t)blockIdx.x * 64;
  for (int i = tid; i < 128 * 64; i += 256) Ws[i] = Wp[i];
#pragma unroll
  for (int i = 0; i < 4; ++i) {
    int c = i * 256 + tid;
    int r = c >> 4, ch = c & 15;
    *(bf16x8*)&Is[r * 128 + ch * 8] = *(const bf16x8*)&in[(row0 + r) * 128 + ch * 8];
  }
  __syncthreads();
  int cg = tid & 15, rs = tid >> 4;  // 16 col-groups x 16 row-slots
  float acc[4][4];
  for (int i = 0; i < 4; ++i)
    for (int j = 0; j < 4; ++j) acc[i][j] = bias[cg * 4 + j];
  for (int kc = 0; kc < 16; ++kc) {
    bf16x8 av[4];
#pragma unroll
    for (int i = 0; i < 4; ++i) av[i] = *(bf16x8*)&Is[(rs + i * 16) * 128 + kc * 8];
#pragma unroll
    for (int e = 0; e < 8; ++e) {
      float4 w4 = *(const float4*)&Ws[(kc * 8 + e) * 64 + cg * 4];
#pragma unroll
      for (int i = 0; i < 4; ++i) {
        float a = bfel(av[i], e);
        acc[i][0] += a * w4.x; acc[i][1] += a * w4.y;
        acc[i][2] += a * w4.z; acc[i][3] += a * w4.w;
      }
    }
  }
  for (int i = 0; i < 4; ++i) {
    int r = rs + i * 16;
    for (int j = 0; j < 4; ++j)
      out[(row0 + r) * 64 + cg * 4 + j] = f2bf(acc[i][j]);
  }
}

// --- v latent projection with transpose: out (B,H,64,T) from (B,T,H,128) ---
__global__ __launch_bounds__(256) void vprojT_kernel(
    const bf16* __restrict__ vb, const float* __restrict__ Wp,
    const float* __restrict__ bias, bf16* __restrict__ vlatT) {
  __shared__ float Ws[128 * 64];
  __shared__ __align__(16) bf16 Is[64 * 128];
  __shared__ __align__(16) bf16 Ot[64 * 64];
  int tid = threadIdx.x;
  int t0 = blockIdx.x * 64, h = blockIdx.y, b = blockIdx.z;
  for (int i = tid; i < 128 * 64; i += 256) Ws[i] = Wp[i];
#pragma unroll
  for (int i = 0; i < 4; ++i) {
    int c = i * 256 + tid;
    int r = c >> 4, ch = c & 15;
    *(bf16x8*)&Is[r * 128 + ch * 8] =
        *(const bf16x8*)&vb[((size_t)(b * TB + t0 + r) * HB + h) * HDB + ch * 8];
  }
  __syncthreads();
  int cg = tid & 15, rs = tid >> 4;
  float acc[4][4];
  for (int i = 0; i < 4; ++i)
    for (int j = 0; j < 4; ++j) acc[i][j] = bias[cg * 4 + j];
  for (int kc = 0; kc < 16; ++kc) {
    bf16x8 av[4];
#pragma unroll
    for (int i = 0; i < 4; ++i) av[i] = *(bf16x8*)&Is[(rs + i * 16) * 128 + kc * 8];
#pragma unroll
    for (int e = 0; e < 8; ++e) {
      float4 w4 = *(const float4*)&Ws[(kc * 8 + e) * 64 + cg * 4];
#pragma unroll
      for (int i = 0; i < 4; ++i) {
        float a = bfel(av[i], e);
        acc[i][0] += a * w4.x; acc[i][1] += a * w4.y;
        acc[i][2] += a * w4.z; acc[i][3] += a * w4.w;
      }
    }
  }
  // transpose via LDS (swizzled): Ot[n][t ^ ((n>>2 & 7)<<3)]
#pragma unroll
  for (int i = 0; i < 4; ++i) {
    int t = rs + i * 16;
    for (int j = 0; j < 4; ++j) {
      int n = cg * 4 + j;
      Ot[n * 64 + (t ^ ((cg & 7) << 3))] = f2bf(acc[i][j]);
    }
  }
  __syncthreads();
#pragma unroll
  for (int i = 0; i < 2; ++i) {
    int c = i * 256 + tid;
    int n = c >> 3, ch = c & 7;
    *(bf16x8*)&vlatT[((size_t)(b * HB + h) * 64 + n) * TB + t0 + ch * 8] =
        *(bf16x8*)&Ot[n * 64 + ((ch ^ ((n >> 2) & 7)) * 8)];
  }
}

// ----------------- causal flash attention over latents (L=64) -------------
// qlat/klat: (B,T,H,L); vlatT: (B,H,L,T); aout: (B,T,H,L).
// Block = q-tile pair {31-p, p}; XCD-chunked mapping keeps a (b,h) on 1 XCD.
__global__ __launch_bounds__(256) void attn_kernel(const bf16* __restrict__ qlat,
                                                   const bf16* __restrict__ klat,
                                                   const bf16* __restrict__ vlatT,
                                                   bf16* __restrict__ aout) {
  int tid = threadIdx.x, w = tid >> 6, l = tid & 63;
  int job = ((int)blockIdx.x & 7) * 64 + ((int)blockIdx.x >> 3);
  int bh = job >> 4, pair = job & 15;
  int h = bh & 15, b = bh >> 4;
  int lrow = l & 15, ck = l >> 4, hi4 = l >> 4;
  __shared__ __align__(16) bf16 Ks[64 * 64];
  __shared__ __align__(16) bf16 VsT[64 * 64];
  __shared__ __align__(16) bf16 Ps[4][16 * 64];
  f32x4 zero4 = {0.f, 0.f, 0.f, 0.f};

  for (int half = 0; half < 2; ++half) {
    int tile = half ? pair : 31 - pair;
    int q0 = tile * 64;
    const bf16* qp = qlat + ((size_t)(b * TB + q0 + w * 16 + lrow) * HB + h) * LB;
    bf16x8 qf0 = *(const bf16x8*)(qp + ck * 8);
    bf16x8 qf1 = *(const bf16x8*)(qp + 32 + ck * 8);
    float mr[4], lsum[4];
    f32x4 o[4];
    for (int r = 0; r < 4; ++r) { mr[r] = -1e30f; lsum[r] = 0.f; }
    for (int n = 0; n < 4; ++n) o[n] = zero4;

    for (int kt = 0; kt <= tile; ++kt) {
      int kv0 = kt * 64;
      __syncthreads();
#pragma unroll
      for (int i = 0; i < 2; ++i) {
        int c = i * 256 + tid;
        int row = c >> 3, ch = c & 7;
        int dst = (c & ~63) * 8;  // wave-uniform element base (lane*16B by HW)
        __builtin_amdgcn_global_load_lds(
            (gvm_t*)(klat + ((size_t)(b * TB + kv0 + row) * HB + h) * LB + ((ch ^ SWZC(row)) * 8)),
            (lds_t*)&Ks[dst], 16, 0, 0);
        __builtin_amdgcn_global_load_lds(
            (gvm_t*)(vlatT + ((size_t)bh * 64 + row) * TB + kv0 + ((ch ^ SWZC(row)) * 8)),
            (lds_t*)&VsT[dst], 16, 0, 0);
      }
      __syncthreads();
      // QK^T: S (16 q x 64 kv) per wave
      f32x4 s[4];
      __builtin_amdgcn_s_setprio(1);
#pragma unroll
      for (int kg = 0; kg < 4; ++kg) {
        int row = kg * 16 + lrow;
        int sw = SWZC(row);
        bf16x8 kf0 = *(bf16x8*)&Ks[row * 64 + ((ck ^ sw) * 8)];
        bf16x8 kf1 = *(bf16x8*)&Ks[row * 64 + (((ck + 4) ^ sw) * 8)];
        f32x4 a = zero4;
        a = MFMA_16x16x32(qf0, kf0, a, 0, 0, 0);
        a = MFMA_16x16x32(qf1, kf1, a, 0, 0, 0);
        s[kg] = a;
      }
      __builtin_amdgcn_s_setprio(0);
      // scale + mask (diag tile only; wave-uniform branch)
      float sc[4][4];
      bool diag = (kt == tile);
#pragma unroll
      for (int kg = 0; kg < 4; ++kg)
#pragma unroll
        for (int r = 0; r < 4; ++r) {
          float v = s[kg][r] * 0.125f;
          if (diag) {
            int kvg = kv0 + kg * 16 + lrow;
            int qr = q0 + w * 16 + 4 * hi4 + r;
            if (kvg > qr) v = -1e30f;
          }
          sc[kg][r] = v;
        }
      // online softmax
      float rm[4], f[4], psum[4];
#pragma unroll
      for (int r = 0; r < 4; ++r)
        rm[r] = fmaxf(fmaxf(sc[0][r], sc[1][r]), fmaxf(sc[2][r], sc[3][r]));
      for (int off = 8; off > 0; off >>= 1)
#pragma unroll
        for (int r = 0; r < 4; ++r) rm[r] = fmaxf(rm[r], __shfl_xor(rm[r], off));
#pragma unroll
      for (int r = 0; r < 4; ++r) {
        float mn = fmaxf(mr[r], rm[r]);
        f[r] = __expf(mr[r] - mn);
        mr[r] = mn;
      }
#pragma unroll
      for (int kg = 0; kg < 4; ++kg)
#pragma unroll
        for (int r = 0; r < 4; ++r) sc[kg][r] = __expf(sc[kg][r] - mr[r]);
#pragma unroll
      for (int r = 0; r < 4; ++r)
        psum[r] = sc[0][r] + sc[1][r] + sc[2][r] + sc[3][r];
      for (int off = 8; off > 0; off >>= 1)
#pragma unroll
        for (int r = 0; r < 4; ++r) psum[r] += __shfl_xor(psum[r], off);
#pragma unroll
      for (int r = 0; r < 4; ++r) lsum[r] = lsum[r] * f[r] + psum[r];
#pragma unroll
      for (int n = 0; n < 4; ++n) {
        f32x4 t = o[n];
        t[0] *= f[0]; t[1] *= f[1]; t[2] *= f[2]; t[3] *= f[3];
        o[n] = t;
      }
      // stage P (per-wave buffer; swizzled)
#pragma unroll
      for (int r = 0; r < 4; ++r) {
        int rq = 4 * hi4 + r;
        int sw8 = SWZC(rq) << 3;
#pragma unroll
        for (int kg = 0; kg < 4; ++kg)
          Ps[w][rq * 64 + ((kg * 16 + lrow) ^ sw8)] = f2bf(sc[kg][r]);
      }
      int swp = SWZC(lrow);
      bf16x8 pa0 = *(bf16x8*)&Ps[w][lrow * 64 + ((ck ^ swp) * 8)];
      bf16x8 pa1 = *(bf16x8*)&Ps[w][lrow * 64 + (((ck + 4) ^ swp) * 8)];
      // PV: o += P @ V
      __builtin_amdgcn_s_setprio(1);
#pragma unroll
      for (int n = 0; n < 4; ++n) {
        int row = n * 16 + lrow;
        int sw = SWZC(row);
        bf16x8 vf0 = *(bf16x8*)&VsT[row * 64 + ((ck ^ sw) * 8)];
        bf16x8 vf1 = *(bf16x8*)&VsT[row * 64 + (((ck + 4) ^ sw) * 8)];
        o[n] = MFMA_16x16x32(pa0, vf0, o[n], 0, 0, 0);
        o[n] = MFMA_16x16x32(pa1, vf1, o[n], 0, 0, 0);
      }
      __builtin_amdgcn_s_setprio(0);
    }
    float inv[4];
#pragma unroll
    for (int r = 0; r < 4; ++r) inv[r] = 1.f / lsum[r];
#pragma unroll
    for (int n = 0; n < 4; ++n)
#pragma unroll
      for (int r = 0; r < 4; ++r) {
        size_t row = (size_t)b * TB + q0 + w * 16 + 4 * hi4 + r;
        aout[(row * HB + h) * LB + n * 16 + lrow] = f2bf(o[n][r] * inv[r]);
      }
  }
}

// ------- output-head projection: (65536 x 64) @ (64x128) + b ---------------
__global__ __launch_bounds__(256) void projd_kernel(const bf16* __restrict__ in,
                                                    const float* __restrict__ Wp,
                                                    const float* __restrict__ bias,
                                                    bf16* __restrict__ out) {
  __shared__ float Ws[64 * 128];
  __shared__ __align__(16) bf16 Is[64 * 64];
  int tid = threadIdx.x;
  size_t row0 = (size_t)blockIdx.x * 64;
  for (int i = tid; i < 64 * 128; i += 256) Ws[i] = Wp[i];
#pragma unroll
  for (int i = 0; i < 2; ++i) {
    int c = i * 256 + tid;
    int r = c >> 3, ch = c & 7;
    *(bf16x8*)&Is[r * 64 + ch * 8] = *(const bf16x8*)&in[(row0 + r) * 64 + ch * 8];
  }
  __syncthreads();
  int cg = tid & 31, rs = tid >> 5;  // 32 col-groups x 8 row-slots
  float acc[8][4];
  for (int i = 0; i < 8; ++i)
    for (int j = 0; j < 4; ++j) acc[i][j] = bias[cg * 4 + j];
  for (int kc = 0; kc < 8; ++kc) {
    bf16x8 av[8];
#pragma unroll
    for (int i = 0; i < 8; ++i) av[i] = *(bf16x8*)&Is[(rs + i * 8) * 64 + kc * 8];
#pragma unroll
    for (int e = 0; e < 8; ++e) {
      float4 w4 = *(const float4*)&Ws[(kc * 8 + e) * 128 + cg * 4];
#pragma unroll
      for (int i = 0; i < 8; ++i) {
        float a = bfel(av[i], e);
        acc[i][0] += a * w4.x; acc[i][1] += a * w4.y;
        acc[i][2] += a * w4.z; acc[i][3] += a * w4.w;
      }
    }
  }
  for (int i = 0; i < 8; ++i) {
    int r = rs + i * 8;
    for (int j = 0; j < 4; ++j)
      out[(row0 + r) * 128 + cg * 4 + j] = f2bf(acc[i][j]);
  }
}

// --------------------------------------------------------------------------
extern "C" void kernel_launch(void* const* d_in, const int* in_sizes, int n_in,
                              void* d_out, int out_size, void* d_ws, size_t ws_size,
                              hipStream_t stream) {
  const float* x    = (const float*)d_in[0];
  const float* ln_w = (const float*)d_in[2];
  const float* ln_b = (const float*)d_in[3];
  const float* wq   = (const float*)d_in[4];
  const float* bq   = (const float*)d_in[5];
  const float* wk   = (const float*)d_in[6];
  const float* bk   = (const float*)d_in[7];
  const float* wv   = (const float*)d_in[8];
  const float* bv   = (const float*)d_in[9];
  const float* wo   = (const float*)d_in[10];
  const float* bo   = (const float*)d_in[11];
  const float* wcq  = (const float*)d_in[12];
  const float* bcq  = (const float*)d_in[13];
  const float* wck  = (const float*)d_in[14];
  const float* bck  = (const float*)d_in[15];
  const float* wcv  = (const float*)d_in[16];
  const float* bcv  = (const float*)d_in[17];
  const float* wd   = (const float*)d_in[18];
  const float* bd   = (const float*)d_in[19];
  const float* fcos = (const float*)d_in[20];
  const float* fsin = (const float*)d_in[21];

  char* ws = (char*)d_ws;
  bf16* xn    = (bf16*)(ws);                  // 16.8 MB [0, 16M)
  bf16* wqkv  = (bf16*)(ws + 16777216);       // 25.2 MB [16M, 42M) (dead after QKV GEMM)
  bf16* qlat  = (bf16*)(ws + 16777216);       //  8.4 MB (overlaps wqkv after it dies)
  bf16* klat  = (bf16*)(ws + 25165824);       //  8.4 MB
  bf16* vlatT = (bf16*)(ws + 33554432);       //  8.4 MB (B,H,64,T)
  bf16* qb_   = (bf16*)(ws + 41943040);       // 16.8 MB
  bf16* kb_   = (bf16*)(ws + 58720256);       // 16.8 MB
  bf16* vb_   = (bf16*)(ws + 75497472);       // 16.8 MB (ends 92.3 MB)
  bf16* aoutp = qb_;   // reuse (q dead after q-latent proj)
  bf16* y1    = xn;    // reuse (xn dead after QKV GEMM)
  bf16* wo_t  = kb_;   // reuse (kb dead after k-latent proj)

  dim3 tg(64, 64);

  ln_kernel<<<MB, 256, 0, stream>>>(x, ln_w, ln_b, xn);

  wconv_kernel<<<tg, 256, 0, stream>>>(wq, wqkv);
  wconv_kernel<<<tg, 256, 0, stream>>>(wk, wqkv + (size_t)2048 * 2048);
  wconv_kernel<<<tg, 256, 0, stream>>>(wv, wqkv + (size_t)4096 * 2048);

  gemm_qkv_kernel<<<dim3(48, 32), 256, 0, stream>>>(xn, wqkv, bq, bk, bv,
                                                    qb_, kb_, vb_, fcos, fsin);

  projqk_kernel<<<dim3(1024, 2), 256, 0, stream>>>(qb_, kb_, wcq, wck, bcq, bck,
                                                   qlat, klat);
  vprojT_kernel<<<dim3(32, 16, 2), 256, 0, stream>>>(vb_, wcv, bcv, vlatT);

  attn_kernel<<<512, 256, 0, stream>>>(qlat, klat, vlatT, aoutp);

  projd_kernel<<<1024, 256, 0, stream>>>(aoutp, wd, bd, y1);

  wconv_kernel<<<tg, 256, 0, stream>>>(wo, wo_t);
  gemm_out_kernel<<<dim3(16, 32), 256, 0, stream>>>(y1, wo_t, bo, (float*)d_out);
}

// Round 5
// 355.839 us; speedup vs baseline: 1.5608x; 1.0094x over previous
//
#include <hip/hip_runtime.h>
#include <hip/hip_bf16.h>
#include <stdint.h>

#define BB 2
#define TB 2048
#define DB 2048
#define HB 16
#define HDB 128
#define LB 64
#define MB 4096   // B*T

typedef __hip_bfloat16 bf16;
typedef __attribute__((ext_vector_type(8))) short bf16x8;
typedef __attribute__((ext_vector_type(4))) float f32x4;

#define MFMA_16x16x32 __builtin_amdgcn_mfma_f32_16x16x32_bf16

typedef __attribute__((address_space(3))) void lds_t;
typedef const __attribute__((address_space(1))) void gvm_t;

static __device__ __forceinline__ float bf2f(bf16 h) { return __bfloat162float(h); }
static __device__ __forceinline__ bf16 f2bf(float f) { return __float2bfloat16(f); }
union BV8 { bf16x8 v; bf16 e[8]; };
static __device__ __forceinline__ float bfel(bf16x8 v, int e) { BV8 u; u.v = v; return bf2f(u.e[e]); }

// chunk-granule XOR swizzle (16B chunks within a 128B row)
#define SWZC(r) (((r) ^ ((r) >> 3)) & 7)

// ---------------- LayerNorm: x (4096,2048) fp32 -> xn bf16 ----------------
__global__ __launch_bounds__(256) void ln_kernel(const float* __restrict__ x,
                                                 const float* __restrict__ g,
                                                 const float* __restrict__ be,
                                                 bf16* __restrict__ xn) {
  int row = blockIdx.x, tid = threadIdx.x;
  const float4* xr = (const float4*)(x + (size_t)row * DB);
  float4 a = xr[2 * tid], b = xr[2 * tid + 1];
  float s = a.x + a.y + a.z + a.w + b.x + b.y + b.z + b.w;
  float s2 = a.x * a.x + a.y * a.y + a.z * a.z + a.w * a.w +
             b.x * b.x + b.y * b.y + b.z * b.z + b.w * b.w;
  for (int off = 32; off > 0; off >>= 1) {
    s += __shfl_down(s, off);
    s2 += __shfl_down(s2, off);
  }
  __shared__ float red[8];
  int w = tid >> 6, lane = tid & 63;
  if (lane == 0) { red[w] = s; red[4 + w] = s2; }
  __syncthreads();
  s = red[0] + red[1] + red[2] + red[3];
  s2 = red[4] + red[5] + red[6] + red[7];
  float mu = s * (1.f / DB);
  float var = s2 * (1.f / DB) - mu * mu;
  float rstd = rsqrtf(var + 1e-5f);
  const float4* gw = (const float4*)g;
  const float4* bb = (const float4*)be;
  float4 g0 = gw[2 * tid], g1 = gw[2 * tid + 1];
  float4 b0 = bb[2 * tid], b1 = bb[2 * tid + 1];
  BV8 u;
  u.e[0] = f2bf((a.x - mu) * rstd * g0.x + b0.x);
  u.e[1] = f2bf((a.y - mu) * rstd * g0.y + b0.y);
  u.e[2] = f2bf((a.z - mu) * rstd * g0.z + b0.z);
  u.e[3] = f2bf((a.w - mu) * rstd * g0.w + b0.w);
  u.e[4] = f2bf((b.x - mu) * rstd * g1.x + b1.x);
  u.e[5] = f2bf((b.y - mu) * rstd * g1.y + b1.y);
  u.e[6] = f2bf((b.z - mu) * rstd * g1.z + b1.z);
  u.e[7] = f2bf((b.w - mu) * rstd * g1.w + b1.w);
  *(bf16x8*)(xn + (size_t)row * DB + tid * 8) = u.v;
}

// ------------- transpose+convert: W fp32 (K,N) -> Wt bf16 (N,K) -----------
__global__ __launch_bounds__(256) void wconv_kernel(const float* __restrict__ W,
                                                    bf16* __restrict__ Wt) {
  __shared__ float t[32][33];
  int c0 = blockIdx.x * 32, r0 = blockIdx.y * 32;
  int tx = threadIdx.x & 31, ty = threadIdx.x >> 5;  // 32 x 8
  for (int p = 0; p < 4; ++p)
    t[ty + 8 * p][tx] = W[(size_t)(r0 + ty + 8 * p) * DB + c0 + tx];
  __syncthreads();
  for (int p = 0; p < 4; ++p)
    Wt[(size_t)(c0 + ty + 8 * p) * DB + r0 + tx] = f2bf(t[tx][ty + 8 * p]);
}

// ---- fold V: BtV[h*64+l][k] = sum_d wv[k][h*128+d] * wcv[d][l] (bf16) ----
__global__ __launch_bounds__(256) void fold_v_kernel(const float* __restrict__ wv,
                                                     const float* __restrict__ wcv,
                                                     bf16* __restrict__ BtV) {
  __shared__ float wvs[128][36];
  int tid = threadIdx.x;
  int k0 = blockIdx.x * 128, h = blockIdx.y;
  int l = tid & 63, ks = tid >> 6;
  float acc[32];
#pragma unroll
  for (int i = 0; i < 32; ++i) acc[i] = 0.f;
  for (int dc = 0; dc < 128; dc += 32) {
    __syncthreads();
    for (int i = tid; i < 128 * 32; i += 256) {
      int kk = i >> 5, dd = i & 31;
      wvs[kk][dd] = wv[(size_t)(k0 + kk) * DB + h * 128 + dc + dd];
    }
    __syncthreads();
    float wr[32];
#pragma unroll
    for (int dd = 0; dd < 32; ++dd) wr[dd] = wcv[(dc + dd) * 64 + l];
#pragma unroll
    for (int i = 0; i < 32; ++i) {
      const float4* row = (const float4*)&wvs[ks * 32 + i][0];
#pragma unroll
      for (int d4 = 0; d4 < 8; ++d4) {
        float4 w4 = row[d4];
        acc[i] += w4.x * wr[d4 * 4] + w4.y * wr[d4 * 4 + 1] +
                  w4.z * wr[d4 * 4 + 2] + w4.w * wr[d4 * 4 + 3];
      }
    }
  }
  bf16* dst = BtV + (size_t)(h * 64 + l) * DB + k0 + ks * 32;
#pragma unroll
  for (int i8 = 0; i8 < 4; ++i8) {
    BV8 u;
#pragma unroll
    for (int j = 0; j < 8; ++j) u.e[j] = f2bf(acc[i8 * 8 + j]);
    *(bf16x8*)(dst + i8 * 8) = u.v;
  }
}

// ---- fold O: BtO[n][h*64+l] = sum_d wo[h*128+d][n] * wd[l][d] (bf16) -----
__global__ __launch_bounds__(256) void fold_o_kernel(const float* __restrict__ wo,
                                                     const float* __restrict__ wd,
                                                     bf16* __restrict__ BtO) {
  __shared__ float wos[32][132];
  int tid = threadIdx.x;
  int n0 = blockIdx.x * 128, h = blockIdx.y;
  int l = tid & 63, ns = tid >> 6;
  float acc[32];
#pragma unroll
  for (int i = 0; i < 32; ++i) acc[i] = 0.f;
  for (int dc = 0; dc < 128; dc += 32) {
    __syncthreads();
    for (int i = tid; i < 32 * 128; i += 256) {
      int dd = i >> 7, nn = i & 127;
      wos[dd][nn] = wo[(size_t)(h * 128 + dc + dd) * DB + n0 + nn];
    }
    __syncthreads();
    float wr[32];
#pragma unroll
    for (int d4 = 0; d4 < 8; ++d4) {
      float4 w4 = *(const float4*)&wd[l * 128 + dc + d4 * 4];
      wr[d4 * 4] = w4.x; wr[d4 * 4 + 1] = w4.y;
      wr[d4 * 4 + 2] = w4.z; wr[d4 * 4 + 3] = w4.w;
    }
#pragma unroll
    for (int dd = 0; dd < 32; ++dd) {
      float w = wr[dd];
      const float4* row = (const float4*)&wos[dd][ns * 32];
#pragma unroll
      for (int i4 = 0; i4 < 8; ++i4) {
        float4 a4 = row[i4];
        acc[i4 * 4 + 0] += a4.x * w; acc[i4 * 4 + 1] += a4.y * w;
        acc[i4 * 4 + 2] += a4.z * w; acc[i4 * 4 + 3] += a4.w * w;
      }
    }
  }
#pragma unroll
  for (int i = 0; i < 32; ++i)
    BtO[(size_t)(n0 + ns * 32 + i) * 1024 + h * 64 + l] = f2bf(acc[i]);
}

// ---- bias folds ----------------------------------------------------------
__global__ __launch_bounds__(256) void biasv_kernel(const float* __restrict__ bv,
                                                    const float* __restrict__ wcv,
                                                    const float* __restrict__ bcv,
                                                    float* __restrict__ bvlat) {
  int j = blockIdx.x * 256 + threadIdx.x;  // 0..1023
  int h = j >> 6, l = j & 63;
  float s = bcv[l];
  for (int d = 0; d < 128; ++d) s += bv[h * 128 + d] * wcv[d * 64 + l];
  bvlat[j] = s;
}

__global__ __launch_bounds__(256) void biaso_kernel(const float* __restrict__ bd,
                                                    const float* __restrict__ wo,
                                                    const float* __restrict__ bo,
                                                    float* __restrict__ bo2) {
  __shared__ float red[4][64];
  int t = threadIdx.x;
  int nl = t & 63, ks = t >> 6;
  int n = blockIdx.x * 64 + nl;  // grid 32
  float s = 0.f;
  for (int k = ks * 512; k < ks * 512 + 512; ++k)
    s += bd[k & 127] * wo[(size_t)k * DB + n];
  red[ks][nl] = s;
  __syncthreads();
  if (ks == 0) bo2[n] = bo[n] + red[0][nl] + red[1][nl] + red[2][nl] + red[3][nl];
}

// ------------- fused QKV+Vlat GEMM: N=5120 = [q 2048 | k 2048 | vlat 1024] -
// A bf16 (4096,2048); wqkT bf16 (4096,2048) rows=[q|k]; BtV bf16 (1024,2048).
// q,k: RoPE epilogue -> qb_/kb_ (t, 2048). vlat: transposed write (B,H,L,T).
__global__ __launch_bounds__(256) void gemm_qkv_kernel(
    const bf16* __restrict__ A, const bf16* __restrict__ wqkT,
    const bf16* __restrict__ BtV,
    const float* __restrict__ bq, const float* __restrict__ bk,
    const float* __restrict__ bvlat,
    bf16* __restrict__ outq, bf16* __restrict__ outk, bf16* __restrict__ vlatT,
    const float* __restrict__ fcos, const float* __restrict__ fsin) {
  constexpr int K = DB;
  __shared__ __align__(16) bf16 As[128 * 32];
  __shared__ __align__(16) bf16 Bs[128 * 32];
  int tid = threadIdx.x;
  int m0 = blockIdx.y * 128, n0 = blockIdx.x * 128;
  int w = tid >> 6, l = tid & 63;
  int wr = w >> 1, wc = w & 1;
  int lrow = l & 15, lk = (l >> 4) * 8;
  const bf16* Bsrc = (n0 < 4096) ? (wqkT + (size_t)n0 * K)
                                 : (BtV + (size_t)(n0 - 4096) * K);

  f32x4 zero4 = {0.f, 0.f, 0.f, 0.f};
  f32x4 acc[4][4];
  for (int m = 0; m < 4; ++m)
    for (int n = 0; n < 4; ++n) acc[m][n] = zero4;

  for (int kk = 0; kk < K / 32; ++kk) {
    int k0 = kk * 32;
    __syncthreads();
#pragma unroll
    for (int i = 0; i < 2; ++i) {
      int c = i * 256 + tid;
      int r = c >> 2, cc = c & 3;
      int cb = i * 256 + (tid & ~63);
      __builtin_amdgcn_global_load_lds(
          (gvm_t*)&A[(size_t)(m0 + r) * K + k0 + cc * 8], (lds_t*)&As[cb * 8], 16, 0, 0);
      __builtin_amdgcn_global_load_lds(
          (gvm_t*)&Bsrc[(size_t)r * K + k0 + cc * 8], (lds_t*)&Bs[cb * 8], 16, 0, 0);
    }
    __syncthreads();
    bf16x8 af[4], bfr[4];
    for (int m = 0; m < 4; ++m)
      af[m] = *(bf16x8*)&As[(wr * 64 + m * 16 + lrow) * 32 + lk];
    for (int n = 0; n < 4; ++n)
      bfr[n] = *(bf16x8*)&Bs[(wc * 64 + n * 16 + lrow) * 32 + lk];
    for (int m = 0; m < 4; ++m)
      for (int n = 0; n < 4; ++n)
        acc[m][n] = MFMA_16x16x32(af[m], bfr[n], acc[m][n], 0, 0, 0);
  }

  int sel = n0 >> 11;  // 0=q, 1=k, 2=vlat (wave-uniform)
  int rg = 4 * (l >> 4), cl = l & 15;
  for (int m = 0; m < 4; ++m) {
    int rowb = m0 + wr * 64 + m * 16 + rg;
    for (int n = 0; n < 4; ++n) {
      int col = n0 + wc * 64 + n * 16 + cl;
      if (sel < 2) {
        int colL = col & 2047;
        float bv_ = (sel == 0 ? bq : bk)[colL];
        bf16* outp = sel == 0 ? outq : outk;
        for (int r = 0; r < 4; ++r) {
          int rr = rowb + r;
          float v = acc[m][n][r] + bv_;
          // RoPE: pairs adjacent cols; parity(col)==parity(lane)
          float pv = __shfl_xor(v, 1);
          int t = rr & (TB - 1);
          int pi = (col & 127) >> 1;
          float c = fcos[t * 64 + pi], sn = fsin[t * 64 + pi];
          v = (col & 1) ? (pv * sn + v * c) : (v * c - pv * sn);
          outp[(size_t)rr * 2048 + colL] = f2bf(v);
        }
      } else {
        int colV = col - 4096;
        float bv_ = bvlat[colV];
        size_t vbase = ((size_t)((rowb >> 11) * HB + (colV >> 6)) * 64 + (colV & 63)) * TB
                       + (rowb & (TB - 1));
        for (int r = 0; r < 4; ++r)
          vlatT[vbase + r] = f2bf(acc[m][n][r] + bv_);
      }
    }
  }
}

// ---------------- final GEMM: out(4096x2048 fp32) = aout(4096x1024)@BtO^T --
__global__ __launch_bounds__(256) void gemm_out_kernel(
    const bf16* __restrict__ A, const bf16* __restrict__ Bt,
    const float* __restrict__ bias, float* __restrict__ Cout) {
  constexpr int K = 1024, N = DB;
  __shared__ __align__(16) bf16 As[128 * 32];
  __shared__ __align__(16) bf16 Bs[128 * 32];
  int tid = threadIdx.x;
  int m0 = blockIdx.y * 128, n0 = blockIdx.x * 128;
  int w = tid >> 6, l = tid & 63;
  int wr = w >> 1, wc = w & 1;
  int lrow = l & 15, lk = (l >> 4) * 8;

  f32x4 zero4 = {0.f, 0.f, 0.f, 0.f};
  f32x4 acc[4][4];
  for (int m = 0; m < 4; ++m)
    for (int n = 0; n < 4; ++n) acc[m][n] = zero4;

  for (int kk = 0; kk < K / 32; ++kk) {
    int k0 = kk * 32;
    __syncthreads();
#pragma unroll
    for (int i = 0; i < 2; ++i) {
      int c = i * 256 + tid;
      int r = c >> 2, cc = c & 3;
      int cb = i * 256 + (tid & ~63);
      __builtin_amdgcn_global_load_lds(
          (gvm_t*)&A[(size_t)(m0 + r) * K + k0 + cc * 8], (lds_t*)&As[cb * 8], 16, 0, 0);
      __builtin_amdgcn_global_load_lds(
          (gvm_t*)&Bt[(size_t)(n0 + r) * K + k0 + cc * 8], (lds_t*)&Bs[cb * 8], 16, 0, 0);
    }
    __syncthreads();
    bf16x8 af[4], bfr[4];
    for (int m = 0; m < 4; ++m)
      af[m] = *(bf16x8*)&As[(wr * 64 + m * 16 + lrow) * 32 + lk];
    for (int n = 0; n < 4; ++n)
      bfr[n] = *(bf16x8*)&Bs[(wc * 64 + n * 16 + lrow) * 32 + lk];
    for (int m = 0; m < 4; ++m)
      for (int n = 0; n < 4; ++n)
        acc[m][n] = MFMA_16x16x32(af[m], bfr[n], acc[m][n], 0, 0, 0);
  }

  int rg = 4 * (l >> 4), cl = l & 15;
  for (int m = 0; m < 4; ++m) {
    int rowb = m0 + wr * 64 + m * 16 + rg;
    for (int n = 0; n < 4; ++n) {
      int col = n0 + wc * 64 + n * 16 + cl;
      float bv = bias[col];
      for (int r = 0; r < 4; ++r)
        Cout[(size_t)(rowb + r) * N + col] = acc[m][n][r] + bv;
    }
  }
}

// ------- q/k latent projection: (65536 x 128) @ (128x64) + b -> (.. x 64) --
__global__ __launch_bounds__(256) void projqk_kernel(
    const bf16* __restrict__ qb, const bf16* __restrict__ kb,
    const float* __restrict__ wcq, const float* __restrict__ wck,
    const float* __restrict__ bcq, const float* __restrict__ bck,
    bf16* __restrict__ qlat, bf16* __restrict__ klat) {
  const bf16* in = blockIdx.y ? kb : qb;
  const float* Wp = blockIdx.y ? wck : wcq;
  const float* bias = blockIdx.y ? bck : bcq;
  bf16* out = blockIdx.y ? klat : qlat;
  __shared__ float Ws[128 * 64];
  __shared__ __align__(16) bf16 Is[64 * 128];
  int tid = threadIdx.x;
  size_t row0 = (size_t)blockIdx.x * 64;
  for (int i = tid; i < 128 * 64; i += 256) Ws[i] = Wp[i];
#pragma unroll
  for (int i = 0; i < 4; ++i) {
    int c = i * 256 + tid;
    int r = c >> 4, ch = c & 15;
    *(bf16x8*)&Is[r * 128 + ch * 8] = *(const bf16x8*)&in[(row0 + r) * 128 + ch * 8];
  }
  __syncthreads();
  int cg = tid & 15, rs = tid >> 4;  // 16 col-groups x 16 row-slots
  float acc[4][4];
  for (int i = 0; i < 4; ++i)
    for (int j = 0; j < 4; ++j) acc[i][j] = bias[cg * 4 + j];
  for (int kc = 0; kc < 16; ++kc) {
    bf16x8 av[4];
#pragma unroll
    for (int i = 0; i < 4; ++i) av[i] = *(bf16x8*)&Is[(rs + i * 16) * 128 + kc * 8];
#pragma unroll
    for (int e = 0; e < 8; ++e) {
      float4 w4 = *(const float4*)&Ws[(kc * 8 + e) * 64 + cg * 4];
#pragma unroll
      for (int i = 0; i < 4; ++i) {
        float a = bfel(av[i], e);
        acc[i][0] += a * w4.x; acc[i][1] += a * w4.y;
        acc[i][2] += a * w4.z; acc[i][3] += a * w4.w;
      }
    }
  }
  for (int i = 0; i < 4; ++i) {
    int r = rs + i * 16;
    for (int j = 0; j < 4; ++j)
      out[(row0 + r) * 64 + cg * 4 + j] = f2bf(acc[i][j]);
  }
}

// ----------------- causal flash attention over latents (L=64) -------------
// qlat/klat: (B,T,H,L); vlatT: (B,H,L,T); aout: (B,T,H,L).
__global__ __launch_bounds__(256) void attn_kernel(const bf16* __restrict__ qlat,
                                                   const bf16* __restrict__ klat,
                                                   const bf16* __restrict__ vlatT,
                                                   bf16* __restrict__ aout) {
  int tid = threadIdx.x, w = tid >> 6, l = tid & 63;
  int job = ((int)blockIdx.x & 7) * 64 + ((int)blockIdx.x >> 3);
  int bh = job >> 4, pair = job & 15;
  int h = bh & 15, b = bh >> 4;
  int lrow = l & 15, ck = l >> 4, hi4 = l >> 4;
  __shared__ __align__(16) bf16 Ks[64 * 64];
  __shared__ __align__(16) bf16 VsT[64 * 64];
  __shared__ __align__(16) bf16 Ps[4][16 * 64];
  f32x4 zero4 = {0.f, 0.f, 0.f, 0.f};

  for (int half = 0; half < 2; ++half) {
    int tile = half ? pair : 31 - pair;
    int q0 = tile * 64;
    const bf16* qp = qlat + ((size_t)(b * TB + q0 + w * 16 + lrow) * HB + h) * LB;
    bf16x8 qf0 = *(const bf16x8*)(qp + ck * 8);
    bf16x8 qf1 = *(const bf16x8*)(qp + 32 + ck * 8);
    float mr[4], lsum[4];
    f32x4 o[4];
    for (int r = 0; r < 4; ++r) { mr[r] = -1e30f; lsum[r] = 0.f; }
    for (int n = 0; n < 4; ++n) o[n] = zero4;

    for (int kt = 0; kt <= tile; ++kt) {
      int kv0 = kt * 64;
      __syncthreads();
#pragma unroll
      for (int i = 0; i < 2; ++i) {
        int c = i * 256 + tid;
        int row = c >> 3, ch = c & 7;
        int dst = (c & ~63) * 8;  // wave-uniform element base (lane*16B by HW)
        __builtin_amdgcn_global_load_lds(
            (gvm_t*)(klat + ((size_t)(b * TB + kv0 + row) * HB + h) * LB + ((ch ^ SWZC(row)) * 8)),
            (lds_t*)&Ks[dst], 16, 0, 0);
        __builtin_amdgcn_global_load_lds(
            (gvm_t*)(vlatT + ((size_t)bh * 64 + row) * TB + kv0 + ((ch ^ SWZC(row)) * 8)),
            (lds_t*)&VsT[dst], 16, 0, 0);
      }
      __syncthreads();
      // QK^T: S (16 q x 64 kv) per wave
      f32x4 s[4];
      __builtin_amdgcn_s_setprio(1);
#pragma unroll
      for (int kg = 0; kg < 4; ++kg) {
        int row = kg * 16 + lrow;
        int sw = SWZC(row);
        bf16x8 kf0 = *(bf16x8*)&Ks[row * 64 + ((ck ^ sw) * 8)];
        bf16x8 kf1 = *(bf16x8*)&Ks[row * 64 + (((ck + 4) ^ sw) * 8)];
        f32x4 a = zero4;
        a = MFMA_16x16x32(qf0, kf0, a, 0, 0, 0);
        a = MFMA_16x16x32(qf1, kf1, a, 0, 0, 0);
        s[kg] = a;
      }
      __builtin_amdgcn_s_setprio(0);
      // scale + mask (diag tile only; wave-uniform branch)
      float sc[4][4];
      bool diag = (kt == tile);
#pragma unroll
      for (int kg = 0; kg < 4; ++kg)
#pragma unroll
        for (int r = 0; r < 4; ++r) {
          float v = s[kg][r] * 0.125f;
          if (diag) {
            int kvg = kv0 + kg * 16 + lrow;
            int qr = q0 + w * 16 + 4 * hi4 + r;
            if (kvg > qr) v = -1e30f;
          }
          sc[kg][r] = v;
        }
      // online softmax
      float rm[4], f[4], psum[4];
#pragma unroll
      for (int r = 0; r < 4; ++r)
        rm[r] = fmaxf(fmaxf(sc[0][r], sc[1][r]), fmaxf(sc[2][r], sc[3][r]));
      for (int off = 8; off > 0; off >>= 1)
#pragma unroll
        for (int r = 0; r < 4; ++r) rm[r] = fmaxf(rm[r], __shfl_xor(rm[r], off));
#pragma unroll
      for (int r = 0; r < 4; ++r) {
        float mn = fmaxf(mr[r], rm[r]);
        f[r] = __expf(mr[r] - mn);
        mr[r] = mn;
      }
#pragma unroll
      for (int kg = 0; kg < 4; ++kg)
#pragma unroll
        for (int r = 0; r < 4; ++r) sc[kg][r] = __expf(sc[kg][r] - mr[r]);
#pragma unroll
      for (int r = 0; r < 4; ++r)
        psum[r] = sc[0][r] + sc[1][r] + sc[2][r] + sc[3][r];
      for (int off = 8; off > 0; off >>= 1)
#pragma unroll
        for (int r = 0; r < 4; ++r) psum[r] += __shfl_xor(psum[r], off);
#pragma unroll
      for (int r = 0; r < 4; ++r) lsum[r] = lsum[r] * f[r] + psum[r];
#pragma unroll
      for (int n = 0; n < 4; ++n) {
        f32x4 t = o[n];
        t[0] *= f[0]; t[1] *= f[1]; t[2] *= f[2]; t[3] *= f[3];
        o[n] = t;
      }
      // stage P (per-wave buffer; swizzled)
#pragma unroll
      for (int r = 0; r < 4; ++r) {
        int rq = 4 * hi4 + r;
        int sw8 = SWZC(rq) << 3;
#pragma unroll
        for (int kg = 0; kg < 4; ++kg)
          Ps[w][rq * 64 + ((kg * 16 + lrow) ^ sw8)] = f2bf(sc[kg][r]);
      }
      int swp = SWZC(lrow);
      bf16x8 pa0 = *(bf16x8*)&Ps[w][lrow * 64 + ((ck ^ swp) * 8)];
      bf16x8 pa1 = *(bf16x8*)&Ps[w][lrow * 64 + (((ck + 4) ^ swp) * 8)];
      // PV: o += P @ V
      __builtin_amdgcn_s_setprio(1);
#pragma unroll
      for (int n = 0; n < 4; ++n) {
        int row = n * 16 + lrow;
        int sw = SWZC(row);
        bf16x8 vf0 = *(bf16x8*)&VsT[row * 64 + ((ck ^ sw) * 8)];
        bf16x8 vf1 = *(bf16x8*)&VsT[row * 64 + (((ck + 4) ^ sw) * 8)];
        o[n] = MFMA_16x16x32(pa0, vf0, o[n], 0, 0, 0);
        o[n] = MFMA_16x16x32(pa1, vf1, o[n], 0, 0, 0);
      }
      __builtin_amdgcn_s_setprio(0);
    }
    float inv[4];
#pragma unroll
    for (int r = 0; r < 4; ++r) inv[r] = 1.f / lsum[r];
#pragma unroll
    for (int n = 0; n < 4; ++n)
#pragma unroll
      for (int r = 0; r < 4; ++r) {
        size_t row = (size_t)b * TB + q0 + w * 16 + 4 * hi4 + r;
        aout[(row * HB + h) * LB + n * 16 + lrow] = f2bf(o[n][r] * inv[r]);
      }
  }
}

// --------------------------------------------------------------------------
extern "C" void kernel_launch(void* const* d_in, const int* in_sizes, int n_in,
                              void* d_out, int out_size, void* d_ws, size_t ws_size,
                              hipStream_t stream) {
  const float* x    = (const float*)d_in[0];
  const float* ln_w = (const float*)d_in[2];
  const float* ln_b = (const float*)d_in[3];
  const float* wq   = (const float*)d_in[4];
  const float* bq   = (const float*)d_in[5];
  const float* wk   = (const float*)d_in[6];
  const float* bk   = (const float*)d_in[7];
  const float* wv   = (const float*)d_in[8];
  const float* bv   = (const float*)d_in[9];
  const float* wo   = (const float*)d_in[10];
  const float* bo   = (const float*)d_in[11];
  const float* wcq  = (const float*)d_in[12];
  const float* bcq  = (const float*)d_in[13];
  const float* wck  = (const float*)d_in[14];
  const float* bck  = (const float*)d_in[15];
  const float* wcv  = (const float*)d_in[16];
  const float* bcv  = (const float*)d_in[17];
  const float* wd   = (const float*)d_in[18];
  const float* bd   = (const float*)d_in[19];
  const float* fcos = (const float*)d_in[20];
  const float* fsin = (const float*)d_in[21];

  char* ws = (char*)d_ws;
  bf16*  xn    = (bf16*)(ws);                 // 16.8 MB; reused: qlat@0, klat@8.4M
  bf16*  wqkT  = (bf16*)(ws + 16777216);      // 16.8 MB (q|k transposed weights)
  bf16*  BtV   = (bf16*)(ws + 33554432);      //  4.2 MB (1024 x 2048)
  bf16*  BtO   = (bf16*)(ws + 37748736);      //  4.2 MB (2048 x 1024)
  bf16*  qb_   = (bf16*)(ws + 41943040);      // 16.8 MB; reused: aout
  bf16*  kb_   = (bf16*)(ws + 58720256);      // 16.8 MB
  bf16*  vlatT = (bf16*)(ws + 75497472);      //  8.4 MB (B,H,L,T)
  float* bvlat = (float*)(ws + 83886080);     //  4 KB
  float* bo2   = (float*)(ws + 83890176);     //  8 KB
  bf16*  qlat  = (bf16*)(ws);                 // reuse xn (dead after QKV GEMM)
  bf16*  klat  = (bf16*)(ws + 8388608);
  bf16*  aoutp = qb_;                         // reuse (q dead after latent proj)

  dim3 tg(64, 64);

  ln_kernel<<<MB, 256, 0, stream>>>(x, ln_w, ln_b, xn);

  wconv_kernel<<<tg, 256, 0, stream>>>(wq, wqkT);
  wconv_kernel<<<tg, 256, 0, stream>>>(wk, wqkT + (size_t)2048 * 2048);
  fold_v_kernel<<<dim3(16, 16), 256, 0, stream>>>(wv, wcv, BtV);
  fold_o_kernel<<<dim3(16, 16), 256, 0, stream>>>(wo, wd, BtO);
  biasv_kernel<<<4, 256, 0, stream>>>(bv, wcv, bcv, bvlat);
  biaso_kernel<<<32, 256, 0, stream>>>(bd, wo, bo, bo2);

  gemm_qkv_kernel<<<dim3(40, 32), 256, 0, stream>>>(
      xn, wqkT, BtV, bq, bk, bvlat, qb_, kb_, vlatT, fcos, fsin);

  projqk_kernel<<<dim3(1024, 2), 256, 0, stream>>>(qb_, kb_, wcq, wck, bcq, bck,
                                                   qlat, klat);

  attn_kernel<<<512, 256, 0, stream>>>(qlat, klat, vlatT, aoutp);

  gemm_out_kernel<<<dim3(16, 32), 256, 0, stream>>>(aoutp, BtO, bo2, (float*)d_out);
}